// Round 1
// baseline (1616.949 us; speedup 1.0000x reference)
//
#include <hip/hip_runtime.h>
#include <stdint.h>

// Problem constants: B=128, S=256, H=512
#define B_ 128
#define S_ 256
#define H_ 512

typedef __attribute__((ext_vector_type(4))) float f32x4;
typedef __attribute__((ext_vector_type(4))) int i32x4;
typedef __attribute__((ext_vector_type(2))) unsigned int u32x2;
typedef __attribute__((ext_vector_type(8))) __bf16 bf16x8;
typedef unsigned long long u64;

// ---------- workspace layout (bytes) ----------
#define OFF_G      0          // 32768 f32 = 131072 B
#define OFF_RSR    131072     // 512 f32
#define OFF_RSH    133120     // 512 f32
#define OFF_FLG    135168     // 64 flags x 64B stride = 4096 B
#define OFF_EX     139264     // 2 parity x 8 groups x 2048 u64 = 262144 B
#define OFF_CBUF   401408     // 128 x 512 f32 = 262144 B
#define OFF_LOGITS 401408     // alias: logits dead before Cb written
#define OFF_BP     663552     // z1_w packed bf16 = 2097152 B
#define OFF_PB     2760704    // scan weights packed bf16 = 1048576 B
// total ~3.81 MB

__device__ __forceinline__ unsigned short f2bf(float f) {
  unsigned u = __builtin_bit_cast(unsigned, f);
  u += 0x7FFFu + ((u >> 16) & 1u);
  return (unsigned short)(u >> 16);
}
__device__ __forceinline__ float fast_sigmoid(float x) {
  return 1.0f / (1.0f + __expf(-x));
}
__device__ __forceinline__ float fast_tanh(float x) {
  return 1.0f - 2.0f / (__expf(2.0f * x) + 1.0f);
}

// Raw barrier with LDS-only drain: does NOT drain vmcnt, so global loads
// issued before it keep flying across (the __syncthreads vmcnt(0) drain is
// exactly what serialized the old scan).
__device__ __forceinline__ void bar_lgkm() {
  asm volatile("s_waitcnt lgkmcnt(0)" ::: "memory");
  __builtin_amdgcn_s_barrier();
  __builtin_amdgcn_sched_barrier(0);
}

// ---------------------------------------------------------------------------
// Prep 1: pack z1_w (2048x512 f32) -> bf16, layout Bp[(k>>3)*512+n][k&7]
// ---------------------------------------------------------------------------
__global__ void k_prep_bp(const float* __restrict__ z1w,
                          unsigned short* __restrict__ Bp) {
  int t = blockIdx.x * blockDim.x + threadIdx.x;  // < 2048*512
  int k = t >> 9, n = t & 511;
  Bp[((k >> 3) * 512 + n) * 8 + (k & 7)] = f2bf(z1w[t]);
}

// ---------------------------------------------------------------------------
// Prep 2: pack Ur,U into per-(mem 0..7, wave 0..7, ktile 0..15, lane) MFMA
// B-fragments. mat = w>>2 (0=Ur,1=U), nt = w&3; n = mem*64 + nt*16 + (l&15).
// ---------------------------------------------------------------------------
__global__ void k_prep_pb(const float* __restrict__ Ur,
                          const float* __restrict__ U,
                          unsigned short* __restrict__ PB) {
  int t = blockIdx.x * blockDim.x + threadIdx.x;  // < 524288
  int j = t & 7;
  int l = (t >> 3) & 63;
  int kt = (t >> 9) & 15;
  int w = (t >> 13) & 7;
  int mem = t >> 16;  // 0..7
  int k = kt * 32 + ((l >> 4) & 3) * 8 + j;
  int n = mem * 64 + (w & 3) * 16 + (l & 15);
  const float* src = (w >> 2) ? U : Ur;
  PB[t] = f2bf(src[k * 512 + n]);
}

// ---------------------------------------------------------------------------
// Prep 3: row sums of Wr and W ('bsh,hk->bsh' collapses to these)
// ---------------------------------------------------------------------------
__global__ void k_prep_rs(const float* __restrict__ Wr,
                          const float* __restrict__ W,
                          float* __restrict__ rsr, float* __restrict__ rsh) {
  __shared__ float red[4];
  int h2 = blockIdx.x;
  int t = threadIdx.x;
  const float* M = (h2 >= 512) ? W : Wr;
  int h = h2 & 511;
  float sv = M[h * 512 + t] + M[h * 512 + 256 + t];
#pragma unroll
  for (int mask = 1; mask < 64; mask <<= 1) sv += __shfl_xor(sv, mask, 64);
  if ((t & 63) == 0) red[t >> 6] = sv;
  __syncthreads();
  if (t == 0) {
    float tot = red[0] + red[1] + red[2] + red[3];
    ((h2 >= 512) ? rsh : rsr)[h] = tot;
  }
}

// ---------------------------------------------------------------------------
// Gate GEMM + fused tanh/dot epilogue (unchanged — not the bottleneck yet)
// ---------------------------------------------------------------------------
__global__ __launch_bounds__(512, 4) void k_gate(
    const float* __restrict__ facts, const float* __restrict__ questions,
    const float* __restrict__ prevM, const float* __restrict__ z1b,
    const float* __restrict__ z2w, const unsigned short* __restrict__ Bp,
    float* __restrict__ logits) {
  __shared__ float qS[512], mS[512], z1bS[512], z2wS[512];
  __shared__ unsigned short At[64 * 40];
  __shared__ unsigned short Bt[16384];
  __shared__ float lp[64 * 4];
  const int tid = threadIdx.x;
  const int row0 = blockIdx.x * 64;
  const int b = row0 >> 8;
  const int s0 = row0 & 255;
  qS[tid] = questions[b * 512 + tid];
  mS[tid] = prevM[b * 512 + tid];
  z1bS[tid] = z1b[tid];
  z2wS[tid] = z2w[tid];
  const int w = tid >> 6, l = tid & 63;
  const int mgrp = w & 1, ngrp = w >> 1;
  const int lm = l & 15, lk = l >> 4;
  f32x4 acc[2][8];
#pragma unroll
  for (int a = 0; a < 2; ++a)
#pragma unroll
    for (int i = 0; i < 8; ++i) acc[a][i] = (f32x4){0.f, 0.f, 0.f, 0.f};
  const int arow = tid >> 3, ac = tid & 7;
  const float* fbase = facts + ((size_t)(b * 256 + s0 + arow)) * 512 + ac * 4;

  for (int kb = 0; kb < 64; ++kb) {
    __syncthreads();
    const int part = kb >> 4;          // 0: f*q, 1: f*m, 2: |f-q|, 3: |f-m|
    const int h0 = (kb & 15) * 32;
    f32x4 fv = *(const f32x4*)(fbase + h0);
    f32x4 ov = (part & 1) ? *(const f32x4*)&mS[h0 + ac * 4]
                          : *(const f32x4*)&qS[h0 + ac * 4];
    float z0, z1, z2, z3;
    if (part < 2) {
      z0 = fv[0] * ov[0]; z1 = fv[1] * ov[1];
      z2 = fv[2] * ov[2]; z3 = fv[3] * ov[3];
    } else {
      z0 = fabsf(fv[0] - ov[0]); z1 = fabsf(fv[1] - ov[1]);
      z2 = fabsf(fv[2] - ov[2]); z3 = fabsf(fv[3] - ov[3]);
    }
    unsigned p0 = (unsigned)f2bf(z0) | ((unsigned)f2bf(z1) << 16);
    unsigned p1 = (unsigned)f2bf(z2) | ((unsigned)f2bf(z3) << 16);
    u32x2 pk = {p0, p1};
    *(u32x2*)&At[arow * 40 + ac * 4] = pk;
    const char* bsrc = (const char*)Bp + (size_t)kb * 32768;
#pragma unroll
    for (int i = 0; i < 4; ++i)
      *(i32x4*)((char*)Bt + i * 8192 + tid * 16) =
          *(const i32x4*)(bsrc + i * 8192 + tid * 16);
    __syncthreads();
    bf16x8 af[2];
#pragma unroll
    for (int mi = 0; mi < 2; ++mi) {
      i32x4 av = *(const i32x4*)&At[((mgrp * 2 + mi) * 16 + lm) * 40 + lk * 8];
      af[mi] = __builtin_bit_cast(bf16x8, av);
    }
#pragma unroll
    for (int i = 0; i < 8; ++i) {
      const int nt = ngrp * 8 + i;
      i32x4 bv = *(const i32x4*)&Bt[lk * 4096 + (nt * 16 + lm) * 8];
      bf16x8 bf = __builtin_bit_cast(bf16x8, bv);
      acc[0][i] = __builtin_amdgcn_mfma_f32_16x16x32_bf16(af[0], bf, acc[0][i], 0, 0, 0);
      acc[1][i] = __builtin_amdgcn_mfma_f32_16x16x32_bf16(af[1], bf, acc[1][i], 0, 0, 0);
    }
  }
  float pr_[2][4];
#pragma unroll
  for (int mi = 0; mi < 2; ++mi)
#pragma unroll
    for (int r = 0; r < 4; ++r) pr_[mi][r] = 0.f;
#pragma unroll
  for (int i = 0; i < 8; ++i) {
    const int n_i = (ngrp * 8 + i) * 16 + lm;
    const float zb = z1bS[n_i], zw = z2wS[n_i];
#pragma unroll
    for (int mi = 0; mi < 2; ++mi)
#pragma unroll
      for (int r = 0; r < 4; ++r)
        pr_[mi][r] += fast_tanh(acc[mi][i][r] + zb) * zw;
  }
#pragma unroll
  for (int mask = 1; mask < 16; mask <<= 1)
#pragma unroll
    for (int mi = 0; mi < 2; ++mi)
#pragma unroll
      for (int r = 0; r < 4; ++r)
        pr_[mi][r] += __shfl_xor(pr_[mi][r], mask, 64);
  if (lm == 0) {
#pragma unroll
    for (int mi = 0; mi < 2; ++mi)
#pragma unroll
      for (int r = 0; r < 4; ++r)
        lp[((mgrp * 2 + mi) * 16 + lk * 4 + r) * 4 + ngrp] = pr_[mi][r];
  }
  __syncthreads();
  if (tid < 64)
    logits[row0 + tid] =
        lp[tid * 4] + lp[tid * 4 + 1] + lp[tid * 4 + 2] + lp[tid * 4 + 3];
}

// ---------------------------------------------------------------------------
// Softmax over S per batch (z2_b dropped: shift-invariant, exact)
// ---------------------------------------------------------------------------
__global__ void k_softmax(const float* __restrict__ logits,
                          float* __restrict__ G) {
  __shared__ float red[4], red2[4];
  int b = blockIdx.x, t = threadIdx.x;
  float v = logits[b * 256 + t];
  float mx = v;
#pragma unroll
  for (int mask = 1; mask < 64; mask <<= 1)
    mx = fmaxf(mx, __shfl_xor(mx, mask, 64));
  if ((t & 63) == 0) red[t >> 6] = mx;
  __syncthreads();
  mx = fmaxf(fmaxf(red[0], red[1]), fmaxf(red[2], red[3]));
  float e = __expf(v - mx);
  float sm = e;
#pragma unroll
  for (int mask = 1; mask < 64; mask <<= 1) sm += __shfl_xor(sm, mask, 64);
  if ((t & 63) == 0) red2[t >> 6] = sm;
  __syncthreads();
  sm = red2[0] + red2[1] + red2[2] + red2[3];
  G[b * 256 + t] = e / sm;
}

// ---------------------------------------------------------------------------
// Scan v4: latency-hiding dual-cohort pipeline.
//
// 32 WGs = 4 supergroups x 8 members. Each WG runs TWO cohorts (groups
// g0=sg*2, g1=sg*2+1) of 16 batches over its 64-wide n-slice; B-fragments
// (VGPR-resident) are shared by both cohorts. Per body (step s), halves
// H0/H1: while cohort c computes (MFMA -> ew -> publish), threads 256..511
// poll + issue the gather loads for the OTHER cohort's next half. All
// barriers are raw s_barrier: BAR1/BAR2 drain lgkmcnt only, BAR3 drains
// vmcnt(0) only on ew-waves (publish visibility before flag). Gather loads
// and facts prefetches (issued one body ahead, post-BAR3) therefore fly
// across barriers instead of being force-drained -> the per-step L3
// round-trips (publish-ack, flag visibility, gather latency) overlap the
// other cohort's compute. Per-thread acquire-spin on exactly the one remote
// member each gather thread reads (8 u64 units -> one member).
// ---------------------------------------------------------------------------
__global__ __launch_bounds__(512, 1) void k_scan(
    const float* __restrict__ facts, const float* __restrict__ Gm,
    const unsigned short* __restrict__ PB, const float* __restrict__ rsr,
    const float* __restrict__ rsh, const float* __restrict__ br,
    const float* __restrict__ bur, const float* __restrict__ bw,
    const float* __restrict__ bu, u64* __restrict__ EXq,
    unsigned int* __restrict__ FLG, float* __restrict__ Cb) {
  __shared__ unsigned short Ash[2][2][16 * 520];  // [cohort][parity][16x512 bf16, 1040B pitch]
  __shared__ float outb[2][8 * 272];              // [cohort][w][row16 pitch17]
  const int tid = threadIdx.x;
  const int mem = blockIdx.x & 7;   // member / n-slice owner
  const int sg = blockIdx.x >> 3;   // supergroup 0..3
  const int w = tid >> 6, l = tid & 63;
  const int lm = l & 15, lk = (l >> 4) & 3;
  // zero A (both cohorts, both parities)
  {
    u64* az = (u64*)Ash;
    for (int i = tid; i < 8320; i += 512) az[i] = 0ull;
  }
  // weight fragments resident in VGPRs: this wave = (mat = w>>2, nt = w&3)
  i32x4 bfr[16];
  const char* pb = (const char*)PB + (size_t)(mem * 8 + w) * 16384;
#pragma unroll
  for (int kt = 0; kt < 16; ++kt)
    bfr[kt] = *(const i32x4*)(pb + kt * 1024 + l * 16);
  // elementwise lane (tid<256): thread owns (bb, 4 consecutive n), x2 cohorts
  const int bb = tid >> 4;           // 0..15
  const int nq = tid & 15;
  const int n0 = mem * 64 + nq * 4;  // global n base
  f32x4 c_rsr, c_br, c_rsh, c_bw, c_bur, c_bu;
  const float* fbase0 = nullptr;
  const float* fbase1 = nullptr;
  const float* gbase0 = nullptr;
  const float* gbase1 = nullptr;
  f32x4 Cv0 = (f32x4){0.f, 0.f, 0.f, 0.f};
  f32x4 Cv1 = (f32x4){0.f, 0.f, 0.f, 0.f};
  f32x4 fct0, fct1;
  float gv0 = 0.f, gv1 = 0.f;
  if (tid < 256) {
    c_rsr = *(const f32x4*)(rsr + n0);
    c_br  = *(const f32x4*)(br + n0);
    c_rsh = *(const f32x4*)(rsh + n0);
    c_bw  = *(const f32x4*)(bw + n0);
    c_bur = *(const f32x4*)(bur + n0);
    c_bu  = *(const f32x4*)(bu + n0);
    const int b0 = (sg * 2 + 0) * 16 + bb;
    const int b1 = (sg * 2 + 1) * 16 + bb;
    fbase0 = facts + (size_t)b0 * 131072 + n0;
    fbase1 = facts + (size_t)b1 * 131072 + n0;
    gbase0 = Gm + b0 * 256;
    gbase1 = Gm + b1 * 256;
    // prefetch step 0 inputs for both cohorts
    fct0 = *(const f32x4*)(fbase0);
    fct1 = *(const f32x4*)(fbase1);
    gv0 = gbase0[0];
    gv1 = gbase1[0];
  }
  // gather lane (tid>=256): 8 u64 units = one (row, member) 64B run
  const int t2 = tid - 256;            // 0..255 (valid for tid>=256)
  const int grow = t2 >> 4;            // row 0..15
  const int gsrc = (t2 & 15) >> 1;     // the single source member for this thread
  const int gnu0 = (t2 & 15) * 8;      // first 8B-unit within row
  u64 gbuf[8];
  __syncthreads();  // prologue barrier (drains prologue loads; fine)

#pragma unroll 1
  for (int s = 0; s < 256; ++s) {
    const int p = s & 1;
#pragma unroll
    for (int c = 0; c < 2; ++c) {
      unsigned short* Ac = &Ash[c][p][0];
      unsigned short* An = &Ash[c][p ^ 1][0];
      f32x4& Cv = (c == 0) ? Cv0 : Cv1;
      f32x4& fct = (c == 0) ? fct0 : fct1;
      float& gv = (c == 0) ? gv0 : gv1;
      const float* fb = (c == 0) ? fbase0 : fbase1;
      const float* gb = (c == 0) ? gbase0 : gbase1;
      // ---- assembly: remote C_s units (gathered last half) -> A_c[p] ----
      if (tid >= 256 && s > 0 && gsrc != mem) {
        u64* dst = (u64*)((char*)Ac + grow * 1040 + gnu0 * 8);
#pragma unroll
        for (int i = 0; i < 8; ++i) dst[i] = gbuf[i];
      }
      bar_lgkm();  // BAR1: A_c[p] fully assembled (LDS-only drain)
      // ---- matvec: (C @ Ur | C @ U) slice via MFMA, two ILP chains ----
      f32x4 acc0 = (f32x4){0.f, 0.f, 0.f, 0.f};
      f32x4 acc1 = (f32x4){0.f, 0.f, 0.f, 0.f};
#pragma unroll
      for (int kt = 0; kt < 16; ++kt) {
        i32x4 av = *(const i32x4*)&Ac[lm * 520 + kt * 32 + lk * 8];
        bf16x8 afv = __builtin_bit_cast(bf16x8, av);
        bf16x8 bfv = __builtin_bit_cast(bf16x8, bfr[kt]);
        if (kt & 1)
          acc1 = __builtin_amdgcn_mfma_f32_16x16x32_bf16(afv, bfv, acc1, 0, 0, 0);
        else
          acc0 = __builtin_amdgcn_mfma_f32_16x16x32_bf16(afv, bfv, acc0, 0, 0, 0);
      }
      f32x4 accs = acc0 + acc1;
#pragma unroll
      for (int r = 0; r < 4; ++r)
        outb[c][w * 272 + (lk * 4 + r) * 17 + lm] = accs[r];
      bar_lgkm();  // BAR2: outb ready (LDS-only drain; prefetches keep flying)
      if (tid < 256) {
        // ---- elementwise update + publish ----
        unsigned short pk[4];
#pragma unroll
        for (int r = 0; r < 4; ++r) {
          const int n_loc = nq * 4 + r;
          const float uro = outb[c][(n_loc >> 4) * 272 + bb * 17 + (n_loc & 15)];
          const float uuo = outb[c][(4 + (n_loc >> 4)) * 272 + bb * 17 + (n_loc & 15)];
          const float pr = fct[r] * c_rsr[r] + c_br[r];
          const float ph = fct[r] * c_rsh[r] + c_bw[r];
          const float r_ = fast_sigmoid(pr + uro + c_bur[r]);
          const float ht = fast_tanh(ph + r_ * (uuo + c_bu[r]));
          Cv[r] = gv * ht + (1.0f - gv) * Cv[r];
          pk[r] = f2bf(Cv[r]);
        }
        const u64 word = (u64)pk[0] | ((u64)pk[1] << 16) | ((u64)pk[2] << 32) |
                         ((u64)pk[3] << 48);
        // own slice straight into next-parity A
        *(u64*)((char*)An + bb * 1040 + n0 * 2) = word;
        // publish payload for the other 7 members
        __hip_atomic_store(
            EXq + ((unsigned)p * 8 + (unsigned)(sg * 2 + c)) * 2048 +
                (unsigned)bb * 128 + (unsigned)(n0 >> 2),
            word, __ATOMIC_RELAXED, __HIP_MEMORY_SCOPE_AGENT);
      } else {
        // ---- poll + issue gather for the NEXT half (other cohort) ----
        const int nc = c ^ 1;
        const int ns = (c == 0) ? s : s + 1;
        if (ns > 0 && ns < 256) {
          const unsigned tagn = (unsigned)ns;
          unsigned* fp =
              FLG + ((unsigned)(sg * 2 + nc) * 8 + (unsigned)gsrc) * 16;
          int guard = 0;
          while (__hip_atomic_load(fp, __ATOMIC_ACQUIRE,
                                   __HIP_MEMORY_SCOPE_AGENT) < tagn) {
            __builtin_amdgcn_s_sleep(1);
            if (++guard > (1 << 22)) break;  // hang-safety bailout
          }
          if (gsrc != mem) {
            const u64* src = EXq +
                ((unsigned)((ns - 1) & 1) * 8 + (unsigned)(sg * 2 + nc)) * 2048 +
                (unsigned)grow * 128 + (unsigned)gnu0;
#pragma unroll
            for (int i = 0; i < 8; ++i)
              gbuf[i] = __hip_atomic_load(src + i, __ATOMIC_RELAXED,
                                          __HIP_MEMORY_SCOPE_AGENT);
            // loads stay in flight across BAR3; consumed at next assembly
          }
        }
      }
      // ---- BAR3: ew-waves drain publish stores; gather loads keep flying ----
      if (tid < 256) asm volatile("s_waitcnt vmcnt(0)" ::: "memory");
      __builtin_amdgcn_s_barrier();
      __builtin_amdgcn_sched_barrier(0);
      if (tid == 0)
        __hip_atomic_store(
            FLG + ((unsigned)(sg * 2 + c) * 8 + (unsigned)mem) * 16,
            (unsigned)(s + 1), __ATOMIC_RELAXED, __HIP_MEMORY_SCOPE_AGENT);
      // ---- prefetch this cohort's next-step inputs (fly across raw bars) ----
      if (tid < 256 && s < 255) {
        fct = *(const f32x4*)(fb + (size_t)(s + 1) * 512);
        gv = gb[s + 1];
      }
    }
  }
  if (tid < 256) {
    *(f32x4*)(Cb + (size_t)((sg * 2 + 0) * 16 + bb) * 512 + n0) = Cv0;
    *(f32x4*)(Cb + (size_t)((sg * 2 + 1) * 16 + bb) * 512 + n0) = Cv1;
  }
}

// ---------------------------------------------------------------------------
// Final: out[b] = relu([prevM | C | questions] @ nm_w + nm_b). 2 batches/WG.
// ---------------------------------------------------------------------------
__global__ __launch_bounds__(512) void k_final(
    const float* __restrict__ prevM, const float* __restrict__ questions,
    const float* __restrict__ Cb, const float* __restrict__ nmw,
    const float* __restrict__ nmb, float* __restrict__ out) {
  __shared__ float cc[2][1536];
  const int t = threadIdx.x;
  const int b0 = blockIdx.x * 2;
  for (int i = t; i < 1536; i += 512) {
#pragma unroll
    for (int bi = 0; bi < 2; ++bi) {
      int bbx = b0 + bi;
      float v;
      if (i < 512) v = prevM[bbx * 512 + i];
      else if (i < 1024) v = Cb[bbx * 512 + i - 512];
      else v = questions[bbx * 512 + i - 1024];
      cc[bi][i] = v;
    }
  }
  __syncthreads();
  const int h = t;
  float a0 = nmb[h], a1 = nmb[h];
#pragma unroll 4
  for (int f = 0; f < 1536; ++f) {
    float wv = nmw[f * 512 + h];
    a0 = fmaf(cc[0][f], wv, a0);
    a1 = fmaf(cc[1][f], wv, a1);
  }
  out[(size_t)b0 * 512 + h] = fmaxf(a0, 0.f);
  out[(size_t)(b0 + 1) * 512 + h] = fmaxf(a1, 0.f);
}

// ---------------------------------------------------------------------------
extern "C" void kernel_launch(void* const* d_in, const int* in_sizes, int n_in,
                              void* d_out, int out_size, void* d_ws,
                              size_t ws_size, hipStream_t stream) {
  const float* facts     = (const float*)d_in[0];
  const float* questions = (const float*)d_in[1];
  const float* prevM     = (const float*)d_in[2];
  const float* z1w       = (const float*)d_in[3];
  const float* z1b       = (const float*)d_in[4];
  const float* z2w       = (const float*)d_in[5];
  // d_in[6] = z2_b: softmax shift-invariant, unused (exact)
  const float* Wr        = (const float*)d_in[7];
  const float* br        = (const float*)d_in[8];
  const float* Ur        = (const float*)d_in[9];
  const float* bur       = (const float*)d_in[10];
  const float* W         = (const float*)d_in[11];
  const float* bw        = (const float*)d_in[12];
  const float* U         = (const float*)d_in[13];
  const float* bu        = (const float*)d_in[14];
  const float* nmw       = (const float*)d_in[15];
  const float* nmb       = (const float*)d_in[16];

  char* ws = (char*)d_ws;
  float* G             = (float*)(ws + OFF_G);
  float* rsr           = (float*)(ws + OFF_RSR);
  float* rsh           = (float*)(ws + OFF_RSH);
  unsigned* FLG        = (unsigned*)(ws + OFF_FLG);
  u64* EXq             = (u64*)(ws + OFF_EX);
  float* Cb            = (float*)(ws + OFF_CBUF);
  float* logits        = (float*)(ws + OFF_LOGITS);
  unsigned short* Bp   = (unsigned short*)(ws + OFF_BP);
  unsigned short* PB   = (unsigned short*)(ws + OFF_PB);

  hipMemsetAsync(FLG, 0, 4096, stream);
  k_prep_bp<<<2048, 512, 0, stream>>>(z1w, Bp);
  k_prep_pb<<<1024, 512, 0, stream>>>(Ur, U, PB);
  k_prep_rs<<<1024, 256, 0, stream>>>(Wr, W, rsr, rsh);
  k_gate<<<512, 512, 0, stream>>>(facts, questions, prevM, z1b, z2w, Bp, logits);
  k_softmax<<<128, 256, 0, stream>>>(logits, G);
  k_scan<<<32, 512, 0, stream>>>(facts, G, PB, rsr, rsh, br, bur, bw, bu, EXq,
                                 FLG, Cb);
  k_final<<<64, 512, 0, stream>>>(prevM, questions, Cb, nmw, nmb, (float*)d_out);
}